// Round 5
// baseline (399.335 us; speedup 1.0000x reference)
//
#include <hip/hip_runtime.h>
#include <stdint.h>

#define NN 100000
#define NE 1600000
#define NG 1000
#define FIN 128
#define DIM 32
#define NC 10

#define NBKT 512          // super-buckets over dst nodes
#define NPB 196           // nodes per bucket (512*196 = 100352 >= NN)
#define BCAP 4608         // edges per bucket (mean 3136 + pad8 ~686 = 3822, ~13 sigma headroom)
#define RND 4096          // edges per binning block (16/thread in regs)
#define CURS 16           // cursor stride in ints (one per 64-B line)
#define NBINB 391         // binning blocks (391*4096 >= NE)
#define NMM1 1563         // mm1 blocks (64 nodes each)
#define MM1P1 781         // mm1 blocks co-dispatched with bin
#define MM1P2 782         // mm1 blocks co-dispatched with csr

typedef unsigned int u32;
typedef __attribute__((ext_vector_type(8))) short short8;
typedef __attribute__((ext_vector_type(4))) float floatx4;
typedef __attribute__((ext_vector_type(4))) unsigned int uint4e;

__device__ __forceinline__ ushort f2bf(float f) {
    u32 b = __float_as_uint(f);
    return (ushort)((b + 0x7FFFu + ((b >> 16) & 1u)) >> 16);   // RNE
}
__device__ __forceinline__ float bf2f(ushort u) {
    return __uint_as_float(((u32)u) << 16);
}

// per-kernel shared unions (keep each as small as possible for occupancy)
struct SBin {                  // 4 KB (no staging: direct global scatter, csr re-sorts anyway)
    int cnt[NBKT]; int gbase[NBKT];
};
struct SCsr {                  // 1.6 KB
    int hist[NPB]; int base[NPB]; int wsum[4];
};
struct SMm {                   // 17.4 KB (x tile only; W frags precomputed)
    ushort xs[64 * 136];
};
union SMem1 { SBin b; SMm m; };   // pre1: 17.4 KB -> 8 blocks/CU
union SMem2 { SCsr c; SMm m; };   // pre2: 17.4 KB -> 8 blocks/CU

// ---------------- init: zero cursor+pool, build bf16 W fragments for all layers ----------------
__global__ __launch_bounds__(256) void k_init(u32* __restrict__ zp, int zn,
        const float* __restrict__ W0r, const float* __restrict__ W0o,
        const float* __restrict__ W1r, const float* __restrict__ W1o,
        const float* __restrict__ W2r, const float* __restrict__ W2o,
        const float* __restrict__ W3r, const float* __restrict__ W3o,
        const float* __restrict__ W4r, const float* __restrict__ W4o,
        ushort* __restrict__ wfrag, ushort* __restrict__ wfrag1) {
    int i = blockIdx.x * 256 + threadIdx.x;
    if (i < zn) zp[i] = 0u;
    int t = threadIdx.x;
    int mat  = t >> 7;          // 0 = rel, 1 = root
    int nh   = (t >> 6) & 1;    // output-col half
    int lane = t & 63;
    int m = lane & 15;          // col within tile
    int g = lane >> 4;          // k-group
    if (blockIdx.x < 4) {       // layers 2..5 (DIM x DIM): one k-chunk each
        const float* Ws[8] = {W1r, W1o, W2r, W2o, W3r, W3o, W4r, W4o};
        const float* W = Ws[blockIdx.x * 2 + mat];
        ushort* dst = wfrag + (((size_t)blockIdx.x * 4 + mat * 2 + nh) * 64 + lane) * 8;
        #pragma unroll
        for (int j = 0; j < 8; ++j)
            dst[j] = f2bf(W[(g * 8 + j) * DIM + nh * 16 + m]);
    } else if (blockIdx.x < 8) { // layer 1 (FIN x DIM): 4 k-chunks
        int kc = blockIdx.x - 4;
        const float* W = mat ? W0o : W0r;
        int nt = mat * 2 + nh;
        ushort* dst = wfrag1 + (((size_t)nt * 4 + kc) * 64 + lane) * 8;
        #pragma unroll
        for (int j = 0; j < 8; ++j)
            dst[j] = f2bf(W[(kc * 32 + g * 8 + j) * DIM + nh * 16 + m]);
    }
}

// ---------------- bodies ----------------
// bin: count-rank via LDS atomics, one cursor atomic per bucket, direct global scatter
// (arrival order within bucket is fine: csr re-sorts by loc)
__device__ void bin_body(SMem1& sm, int blk, const int* __restrict__ ei,
        const float* __restrict__ ew, int* __restrict__ cursor,
        uint2* __restrict__ ebuf) {
    int tid = threadIdx.x;
    int e0 = blk * RND;
    int n  = min(RND, NE - e0);

    for (int i = tid; i < NBKT; i += 256) sm.b.cnt[i] = 0;
    __syncthreads();

    u32 pk[16], wvv[16], bp[16];
    #pragma unroll
    for (int q = 0; q < 16; ++q) {
        int i = tid + q * 256;
        bp[q] = 0xFFFFFFFFu;
        if (i < n) {
            int s = ei[e0 + i];
            int d = ei[NE + e0 + i];
            float w = ew[e0 + i];
            int b = d / NPB;
            int loc = d - b * NPB;
            int p = atomicAdd(&sm.b.cnt[b], 1);
            pk[q]  = (u32)s | ((u32)loc << 17);
            wvv[q] = __float_as_uint(w);
            bp[q]  = (u32)p | ((u32)b << 16);
        }
    }
    __syncthreads();

    for (int i = tid; i < NBKT; i += 256) {
        int c = sm.b.cnt[i];
        sm.b.gbase[i] = (c > 0) ? atomicAdd(&cursor[i * CURS], c) : 0;
    }
    __syncthreads();

    #pragma unroll
    for (int q = 0; q < 16; ++q) {
        if (bp[q] != 0xFFFFFFFFu) {
            int b = (int)(bp[q] >> 16);
            int p = (int)(bp[q] & 0xFFFFu);
            int pos = sm.b.gbase[b] + p;
            if (pos < BCAP) ebuf[(size_t)b * BCAP + pos] = make_uint2(pk[q], wvv[q]);
        }
    }
}

__device__ void csr_body(SMem2& sm, int bkt, uint2* __restrict__ ebuf,
        const int* __restrict__ cursor, uint2* __restrict__ od) {
    int tid = threadIdx.x;
    int lane = tid & 63, wvx = tid >> 6;
    int cnt = min(cursor[bkt * CURS], 4096);     // 16 regs/thread capacity
    for (int i = tid; i < NPB; i += 256) sm.c.hist[i] = 0;
    __syncthreads();
    uint2* gb = ebuf + (size_t)bkt * BCAP;
    uint2 my[16]; int mp[16];
    #pragma unroll
    for (int q = 0; q < 16; ++q) {
        int i = tid + q * 256;
        mp[q] = -1;
        if (i < cnt) {
            my[q] = gb[i];
            int loc = (int)(my[q].x >> 17);
            mp[q] = atomicAdd(&sm.c.hist[loc], 1);
        }
    }
    __syncthreads();
    // padded (x8) exclusive scan over 196 hist entries via wave shuffles
    int h  = (tid < NPB) ? sm.c.hist[tid] : 0;
    int hp = (h + 7) & ~7;
    int inc = hp;
    #pragma unroll
    for (int d = 1; d < 64; d <<= 1) {
        int u = __shfl_up(inc, d);
        if (lane >= d) inc += u;
    }
    if (lane == 63) sm.c.wsum[wvx] = inc;
    __syncthreads();
    int off = 0;
    #pragma unroll
    for (int w2 = 0; w2 < 3; ++w2) off += (w2 < wvx) ? sm.c.wsum[w2] : 0;
    if (tid < NPB) sm.c.base[tid] = off + inc - hp;
    __syncthreads();
    int tot = sm.c.wsum[0] + sm.c.wsum[1] + sm.c.wsum[2] + sm.c.wsum[3];
    tot = min(tot, BCAP);
    // zero-fill padded region (coalesced), then scatter sorted entries directly to global;
    // bucket is block-private and L2-resident, so the double write is absorbed by L2
    for (int i = tid; i < tot; i += 256) gb[i] = make_uint2(0u, 0u);
    __syncthreads();
    #pragma unroll
    for (int q = 0; q < 16; ++q) {
        if (mp[q] >= 0) {
            int loc = (int)(my[q].x >> 17);
            int pos = sm.c.base[loc] + mp[q];
            if (pos < BCAP) gb[pos] = my[q];
        }
    }
    for (int i = tid; i < NPB; i += 256) {
        int node = bkt * NPB + i;
        if (node < NN) {
            int dg = sm.c.hist[i];
            int bs = sm.c.base[i];
            if (bs + ((dg + 7) & ~7) > BCAP) dg = max(0, BCAP - bs) & ~7;   // ~never
            od[node] = make_uint2((u32)(bkt * BCAP + bs), (u32)dg);
        }
    }
}

__device__ void mm1_body(ushort* __restrict__ xs, int blk, const float* __restrict__ x,
        const ushort* __restrict__ wfrag1, const float* __restrict__ brel,
        ushort* __restrict__ ybf, float* __restrict__ aggi) {
    int tid = threadIdx.x;
    int base = blk * 64;
    for (int i = tid; i < 64 * 32; i += 256) {
        int r = i >> 5, c = i & 31;
        int node = base + r;
        float4 v = make_float4(0.f, 0.f, 0.f, 0.f);
        if (node < NN) v = ((const float4*)x)[(size_t)node * 32 + c];
        ushort4 u;
        u.x = f2bf(v.x); u.y = f2bf(v.y); u.z = f2bf(v.z); u.w = f2bf(v.w);
        *(ushort4*)&xs[r * 136 + c * 4] = u;
    }
    int lane = tid & 63;
    int w = tid >> 6;
    int m = lane & 15;
    int q = lane >> 4;
    // W fragments direct from global (hot in L2; identical bf16 values as before)
    short8 bfr[4][4];
    #pragma unroll
    for (int nt = 0; nt < 4; ++nt)
        #pragma unroll
        for (int kc = 0; kc < 4; ++kc)
            bfr[nt][kc] = *(const short8*)&wfrag1[(((size_t)nt * 4 + kc) * 64 + lane) * 8];
    __syncthreads();
    floatx4 acc[4] = {{0.f,0.f,0.f,0.f},{0.f,0.f,0.f,0.f},{0.f,0.f,0.f,0.f},{0.f,0.f,0.f,0.f}};
    #pragma unroll
    for (int kc = 0; kc < 4; ++kc) {
        short8 af = *(const short8*)&xs[(w * 16 + m) * 136 + kc * 32 + q * 8];
        #pragma unroll
        for (int nt = 0; nt < 4; ++nt)
            acc[nt] = __builtin_amdgcn_mfma_f32_16x16x32_bf16(af, bfr[nt][kc], acc[nt], 0, 0, 0);
    }
    float br0 = brel[m], br1 = brel[16 + m];
    #pragma unroll
    for (int reg = 0; reg < 4; ++reg) {
        int row = q * 4 + reg;
        int node = base + w * 16 + row;
        if (node < NN) {
            ybf[(size_t)node * 32 + m]       = f2bf(acc[0][reg]);
            ybf[(size_t)node * 32 + 16 + m]  = f2bf(acc[1][reg]);
            aggi[(size_t)node * 32 + m]      = acc[2][reg] + br0;
            aggi[(size_t)node * 32 + 16 + m] = acc[3][reg] + br1;
        }
    }
}

// ---------------- combined dispatches: bin || mm1-half1, csr || mm1-half2 ----------------
__global__ __launch_bounds__(256, 8) void k_pre1(const int* __restrict__ ei,
        const float* __restrict__ ew, int* __restrict__ cursor, uint2* __restrict__ ebuf,
        const float* __restrict__ x, const ushort* __restrict__ wfrag1,
        const float* __restrict__ brel,
        ushort* __restrict__ ybf, float* __restrict__ aggi) {
    __shared__ SMem1 sm;
    if (blockIdx.x < NBINB) bin_body(sm, blockIdx.x, ei, ew, cursor, ebuf);
    else                    mm1_body(sm.m.xs, blockIdx.x - NBINB, x, wfrag1, brel, ybf, aggi);
}

__global__ __launch_bounds__(256, 8) void k_pre2(uint2* __restrict__ ebuf,
        const int* __restrict__ cursor, uint2* __restrict__ od,
        const float* __restrict__ x, const ushort* __restrict__ wfrag1,
        const float* __restrict__ brel,
        ushort* __restrict__ ybf, float* __restrict__ aggi) {
    __shared__ SMem2 sm;
    if (blockIdx.x < NBKT) csr_body(sm, blockIdx.x, ebuf, cursor, od);
    else                   mm1_body(sm.m.xs, blockIdx.x - NBKT + MM1P1, x, wfrag1, brel, ybf, aggi);
}

// ---------------- packed 2-feature gather: 16 lanes/node, 16-edge strips for MLP ----------------
// pad-to-8 invariant: a 16-strip at b is entered only when deg >= b+9, so padded len >= b+16
__device__ __forceinline__ float2 gather_accum(const uint2* __restrict__ eb, int deg,
        const uint* __restrict__ ybp) {
    float acc0 = 0.f, acc1 = 0.f;
    int b = 0;
    for (; b + 8 < deg; b += 16) {
        const uint4e* p = (const uint4e*)(eb + b);
        uint4e e0 = __builtin_nontemporal_load(p + 0);
        uint4e e1 = __builtin_nontemporal_load(p + 1);
        uint4e e2 = __builtin_nontemporal_load(p + 2);
        uint4e e3 = __builtin_nontemporal_load(p + 3);
        uint4e e4 = __builtin_nontemporal_load(p + 4);
        uint4e e5 = __builtin_nontemporal_load(p + 5);
        uint4e e6 = __builtin_nontemporal_load(p + 6);
        uint4e e7 = __builtin_nontemporal_load(p + 7);
        uint u0  = ybp[(e0.x & 0x1FFFFu) << 4];
        uint u1  = ybp[(e0.z & 0x1FFFFu) << 4];
        uint u2  = ybp[(e1.x & 0x1FFFFu) << 4];
        uint u3  = ybp[(e1.z & 0x1FFFFu) << 4];
        uint u4  = ybp[(e2.x & 0x1FFFFu) << 4];
        uint u5  = ybp[(e2.z & 0x1FFFFu) << 4];
        uint u6  = ybp[(e3.x & 0x1FFFFu) << 4];
        uint u7  = ybp[(e3.z & 0x1FFFFu) << 4];
        uint u8  = ybp[(e4.x & 0x1FFFFu) << 4];
        uint u9  = ybp[(e4.z & 0x1FFFFu) << 4];
        uint u10 = ybp[(e5.x & 0x1FFFFu) << 4];
        uint u11 = ybp[(e5.z & 0x1FFFFu) << 4];
        uint u12 = ybp[(e6.x & 0x1FFFFu) << 4];
        uint u13 = ybp[(e6.z & 0x1FFFFu) << 4];
        uint u14 = ybp[(e7.x & 0x1FFFFu) << 4];
        uint u15 = ybp[(e7.z & 0x1FFFFu) << 4];
        acc0 += __uint_as_float(e0.y) * __uint_as_float(u0 << 16);
        acc1 += __uint_as_float(e0.y) * __uint_as_float(u0 & 0xFFFF0000u);
        acc0 += __uint_as_float(e0.w) * __uint_as_float(u1 << 16);
        acc1 += __uint_as_float(e0.w) * __uint_as_float(u1 & 0xFFFF0000u);
        acc0 += __uint_as_float(e1.y) * __uint_as_float(u2 << 16);
        acc1 += __uint_as_float(e1.y) * __uint_as_float(u2 & 0xFFFF0000u);
        acc0 += __uint_as_float(e1.w) * __uint_as_float(u3 << 16);
        acc1 += __uint_as_float(e1.w) * __uint_as_float(u3 & 0xFFFF0000u);
        acc0 += __uint_as_float(e2.y) * __uint_as_float(u4 << 16);
        acc1 += __uint_as_float(e2.y) * __uint_as_float(u4 & 0xFFFF0000u);
        acc0 += __uint_as_float(e2.w) * __uint_as_float(u5 << 16);
        acc1 += __uint_as_float(e2.w) * __uint_as_float(u5 & 0xFFFF0000u);
        acc0 += __uint_as_float(e3.y) * __uint_as_float(u6 << 16);
        acc1 += __uint_as_float(e3.y) * __uint_as_float(u6 & 0xFFFF0000u);
        acc0 += __uint_as_float(e3.w) * __uint_as_float(u7 << 16);
        acc1 += __uint_as_float(e3.w) * __uint_as_float(u7 & 0xFFFF0000u);
        acc0 += __uint_as_float(e4.y) * __uint_as_float(u8 << 16);
        acc1 += __uint_as_float(e4.y) * __uint_as_float(u8 & 0xFFFF0000u);
        acc0 += __uint_as_float(e4.w) * __uint_as_float(u9 << 16);
        acc1 += __uint_as_float(e4.w) * __uint_as_float(u9 & 0xFFFF0000u);
        acc0 += __uint_as_float(e5.y) * __uint_as_float(u10 << 16);
        acc1 += __uint_as_float(e5.y) * __uint_as_float(u10 & 0xFFFF0000u);
        acc0 += __uint_as_float(e5.w) * __uint_as_float(u11 << 16);
        acc1 += __uint_as_float(e5.w) * __uint_as_float(u11 & 0xFFFF0000u);
        acc0 += __uint_as_float(e6.y) * __uint_as_float(u12 << 16);
        acc1 += __uint_as_float(e6.y) * __uint_as_float(u12 & 0xFFFF0000u);
        acc0 += __uint_as_float(e6.w) * __uint_as_float(u13 << 16);
        acc1 += __uint_as_float(e6.w) * __uint_as_float(u13 & 0xFFFF0000u);
        acc0 += __uint_as_float(e7.y) * __uint_as_float(u14 << 16);
        acc1 += __uint_as_float(e7.y) * __uint_as_float(u14 & 0xFFFF0000u);
        acc0 += __uint_as_float(e7.w) * __uint_as_float(u15 << 16);
        acc1 += __uint_as_float(e7.w) * __uint_as_float(u15 & 0xFFFF0000u);
    }
    if (b < deg) {                                  // 8-edge tail (deg%16 in 1..8)
        const uint4e* p = (const uint4e*)(eb + b);
        uint4e e0 = __builtin_nontemporal_load(p + 0);
        uint4e e1 = __builtin_nontemporal_load(p + 1);
        uint4e e2 = __builtin_nontemporal_load(p + 2);
        uint4e e3 = __builtin_nontemporal_load(p + 3);
        uint u0 = ybp[(e0.x & 0x1FFFFu) << 4];
        uint u1 = ybp[(e0.z & 0x1FFFFu) << 4];
        uint u2 = ybp[(e1.x & 0x1FFFFu) << 4];
        uint u3 = ybp[(e1.z & 0x1FFFFu) << 4];
        uint u4 = ybp[(e2.x & 0x1FFFFu) << 4];
        uint u5 = ybp[(e2.z & 0x1FFFFu) << 4];
        uint u6 = ybp[(e3.x & 0x1FFFFu) << 4];
        uint u7 = ybp[(e3.z & 0x1FFFFu) << 4];
        acc0 += __uint_as_float(e0.y) * __uint_as_float(u0 << 16);
        acc1 += __uint_as_float(e0.y) * __uint_as_float(u0 & 0xFFFF0000u);
        acc0 += __uint_as_float(e0.w) * __uint_as_float(u1 << 16);
        acc1 += __uint_as_float(e0.w) * __uint_as_float(u1 & 0xFFFF0000u);
        acc0 += __uint_as_float(e1.y) * __uint_as_float(u2 << 16);
        acc1 += __uint_as_float(e1.y) * __uint_as_float(u2 & 0xFFFF0000u);
        acc0 += __uint_as_float(e1.w) * __uint_as_float(u3 << 16);
        acc1 += __uint_as_float(e1.w) * __uint_as_float(u3 & 0xFFFF0000u);
        acc0 += __uint_as_float(e2.y) * __uint_as_float(u4 << 16);
        acc1 += __uint_as_float(e2.y) * __uint_as_float(u4 & 0xFFFF0000u);
        acc0 += __uint_as_float(e2.w) * __uint_as_float(u5 << 16);
        acc1 += __uint_as_float(e2.w) * __uint_as_float(u5 & 0xFFFF0000u);
        acc0 += __uint_as_float(e3.y) * __uint_as_float(u6 << 16);
        acc1 += __uint_as_float(e3.y) * __uint_as_float(u6 & 0xFFFF0000u);
        acc0 += __uint_as_float(e3.w) * __uint_as_float(u7 << 16);
        acc1 += __uint_as_float(e3.w) * __uint_as_float(u7 & 0xFFFF0000u);
    }
    return make_float2(acc0, acc1);
}

// ---------------- fused gather + relu + next-layer dual matmul (MFMA) ----------------
// 16 nodes/block, 4 waves: wave w computes one 16x16 output tile (mat = w>>1, colhalf = w&1)
__global__ __launch_bounds__(256, 8) void k_gfused(const ushort* __restrict__ ybf,
        const uint2* __restrict__ ebuf, const uint2* __restrict__ od,
        const float* __restrict__ aggi, const ushort* __restrict__ wfragL,
        const float* __restrict__ brel,
        ushort* __restrict__ ybf_n, float* __restrict__ aggi_n) {
    __shared__ __align__(16) ushort hsm[16 * 40];   // h tile, bf16, pitch 40 shorts
    int tid  = threadIdx.x;
    int w    = tid >> 6;
    int lane = tid & 63;
    int nl   = lane >> 4;        // node within wave
    int fp   = lane & 15;        // feature pair index
    int node = blockIdx.x * 16 + w * 4 + nl;
    // wave-specific W fragment (precomputed bf16, fragment-major): one 16-B load
    short8 bfr = *(const short8*)&wfragL[((size_t)w * 64 + lane) * 8];
    uint2 o = od[node];
    const uint2* eb = ebuf + o.x;
    const uint* ybp = (const uint*)ybf + fp;
    float2 pv = *(const float2*)&aggi[(size_t)node * DIM + fp * 2];
    float2 ac = gather_accum(eb, (int)o.y, ybp);
    float h0 = fmaxf(pv.x + ac.x, 0.f);
    float h1 = fmaxf(pv.y + ac.y, 0.f);
    u32 hp = (u32)f2bf(h0) | ((u32)f2bf(h1) << 16);
    *(u32*)&hsm[(w * 4 + nl) * 40 + fp * 2] = hp;
    __syncthreads();
    // A fragment: lane reads h[row = lane&15][k = (lane>>4)*8 .. +7]
    short8 af = *(const short8*)&hsm[(lane & 15) * 40 + (lane >> 4) * 8];
    floatx4 acc = {0.f, 0.f, 0.f, 0.f};
    acc = __builtin_amdgcn_mfma_f32_16x16x32_bf16(af, bfr, acc, 0, 0, 0);
    int ncol  = (w & 1) * 16 + (lane & 15);
    int drow0 = (lane >> 4) * 4;
    size_t obase = ((size_t)blockIdx.x * 16 + drow0) * DIM + ncol;
    if (w < 2) {                                   // rel path -> y (bf16)
        #pragma unroll
        for (int r = 0; r < 4; ++r)
            ybf_n[obase + (size_t)r * DIM] = f2bf(acc[r]);
    } else {                                       // root path + bias -> agg init (f32)
        float bb = brel[ncol];
        #pragma unroll
        for (int r = 0; r < 4; ++r)
            __builtin_nontemporal_store(acc[r] + bb, &aggi_n[obase + (size_t)r * DIM]);
    }
}

// ---------------- fused last gather + relu + pool ----------------
__global__ __launch_bounds__(256, 8) void k_glast_pool(const ushort* __restrict__ ybf,
        const uint2* __restrict__ ebuf, const uint2* __restrict__ od,
        const float* __restrict__ aggi, const int* __restrict__ batch,
        float* __restrict__ g) {
    __shared__ __align__(16) float hsm[16][34];
    int tid  = threadIdx.x;
    int w    = tid >> 6;
    int lane = tid & 63;
    int nl   = lane >> 4;
    int fp   = lane & 15;
    int node = blockIdx.x * 16 + w * 4 + nl;
    uint2 o = od[node];
    const uint2* eb = ebuf + o.x;
    const uint* ybp = (const uint*)ybf + fp;
    float2 pv = *(const float2*)&aggi[(size_t)node * DIM + fp * 2];
    float2 ac = gather_accum(eb, (int)o.y, ybp);
    float2 hv;
    hv.x = fmaxf(pv.x + ac.x, 0.f);
    hv.y = fmaxf(pv.y + ac.y, 0.f);
    *(float2*)&hsm[w * 4 + nl][fp * 2] = hv;
    __syncthreads();
    if (tid < 32) {                            // segmented sum over 16 sorted nodes
        int nb = blockIdx.x * 16;
        int curb = batch[nb];
        float run = 0.f;
        #pragma unroll
        for (int n = 0; n < 16; ++n) {
            int b = batch[nb + n];
            if (b != curb) {
                atomicAdd(&g[(size_t)curb * DIM + tid], run);
                run = 0.f; curb = b;
            }
            run += hsm[n][tid];
        }
        atomicAdd(&g[(size_t)curb * DIM + tid], run);
    }
}

// ---------------- head ----------------
__global__ __launch_bounds__(64) void k_head(const float* __restrict__ g,
        const float* __restrict__ W1, const float* __restrict__ b1,
        const float* __restrict__ W2, const float* __restrict__ b2,
        float* __restrict__ out) {
    __shared__ float gs[DIM];
    __shared__ float a1[DIM];
    __shared__ float lg[NC];
    int t = threadIdx.x;
    int gr = blockIdx.x;
    if (t < DIM) gs[t] = g[(size_t)gr * DIM + t];
    __syncthreads();
    if (t < DIM) {
        float a = b1[t];
        #pragma unroll
        for (int k = 0; k < DIM; ++k) a += gs[k] * W1[k * DIM + t];
        a1[t] = fmaxf(a, 0.f);
    }
    __syncthreads();
    if (t < NC) {
        float a = b2[t];
        #pragma unroll
        for (int k = 0; k < DIM; ++k) a += a1[k] * W2[k * NC + t];
        lg[t] = a;
    }
    __syncthreads();
    if (t == 0) {
        float m = lg[0];
        for (int c = 1; c < NC; ++c) m = fmaxf(m, lg[c]);
        float s = 0.f;
        for (int c = 0; c < NC; ++c) s += expf(lg[c] - m);
        float ls = m + logf(s);
        for (int c = 0; c < NC; ++c) out[(size_t)gr * NC + c] = lg[c] - ls;
    }
}

extern "C" void kernel_launch(void* const* d_in, const int* in_sizes, int n_in,
                              void* d_out, int out_size, void* d_ws, size_t ws_size,
                              hipStream_t stream) {
    const float* x     = (const float*)d_in[0];
    const int*   ei    = (const int*)d_in[1];
    const int*   batch = (const int*)d_in[2];
    const float* ew    = (const float*)d_in[3];
    const float* Wrel[5]  = {(const float*)d_in[4],  (const float*)d_in[7],  (const float*)d_in[10], (const float*)d_in[13], (const float*)d_in[16]};
    const float* brel[5]  = {(const float*)d_in[5],  (const float*)d_in[8],  (const float*)d_in[11], (const float*)d_in[14], (const float*)d_in[17]};
    const float* Wroot[5] = {(const float*)d_in[6],  (const float*)d_in[9],  (const float*)d_in[12], (const float*)d_in[15], (const float*)d_in[18]};
    const float* W1 = (const float*)d_in[19];
    const float* b1 = (const float*)d_in[20];
    const float* W2 = (const float*)d_in[21];
    const float* b2 = (const float*)d_in[22];
    float* out = (float*)d_out;

    char* ws = (char*)d_ws;
    const size_t off_cursor = 0;                                   // 32768
    const size_t off_g      = 32768;                               // 128000
    const size_t zero_end   = 160768;
    const size_t off_wfrag  = 160768;                              // layers 2-5: 16384 B
    const size_t off_wfrag1 = 177152;                              // layer 1: 16384 B
    const size_t off_ebuf   = 193536;                              // 16-B aligned
    const size_t ebuf_bytes = ((size_t)NBKT * BCAP + 64) * 8;
    const size_t off_od     = off_ebuf + ebuf_bytes;
    const size_t off_A      = off_od + (size_t)NN * 8;             // aggi ping
    const size_t off_C      = off_A + (size_t)NN * DIM * 4;        // aggi pong
    const size_t off_B1     = off_C + (size_t)NN * DIM * 4;        // y ping (bf16)
    const size_t off_B2     = off_B1 + (size_t)NN * DIM * 2;       // y pong (bf16)
    const size_t need       = off_B2 + (size_t)NN * DIM * 2;       // ~58.3 MB
    if (ws_size < need) return;

    int*    cursor = (int*)(ws + off_cursor);
    float*  g      = (float*)(ws + off_g);
    ushort* wfrag  = (ushort*)(ws + off_wfrag);
    ushort* wfrag1 = (ushort*)(ws + off_wfrag1);
    uint2*  ebuf   = (uint2*)(ws + off_ebuf);
    uint2*  od     = (uint2*)(ws + off_od);
    float*  A      = (float*)(ws + off_A);
    float*  C      = (float*)(ws + off_C);
    ushort* B1     = (ushort*)(ws + off_B1);
    ushort* B2     = (ushort*)(ws + off_B2);

    int zcount = (int)(zero_end / 4);
    k_init<<<(zcount + 255) / 256, 256, 0, stream>>>((u32*)ws, zcount,
        Wrel[0], Wroot[0], Wrel[1], Wroot[1], Wrel[2], Wroot[2],
        Wrel[3], Wroot[3], Wrel[4], Wroot[4], wfrag, wfrag1);

    // combined: binning || mm1 first half, then csr || mm1 second half
    k_pre1<<<NBINB + MM1P1, 256, 0, stream>>>(ei, ew, cursor, ebuf,
                                              x, wfrag1, brel[0], B1, A);
    k_pre2<<<NBKT + MM1P2, 256, 0, stream>>>(ebuf, cursor, od,
                                             x, wfrag1, brel[0], B1, A);

    const int ngt = NN / 16;                   // 6250 (exact)
    float*  aggc = A;  float*  aggn = C;
    ushort* yc   = B1; ushort* yn   = B2;
    for (int L = 1; L < 5; ++L) {
        k_gfused<<<ngt, 256, 0, stream>>>(yc, ebuf, od, aggc,
                                          wfrag + (size_t)(L - 1) * 2048, brel[L], yn, aggn);
        float* tf = aggc; aggc = aggn; aggn = tf;
        ushort* tu = yc; yc = yn; yn = tu;
    }
    k_glast_pool<<<ngt, 256, 0, stream>>>(yc, ebuf, od, aggc, batch, g);
    k_head<<<NG, 64, 0, stream>>>(g, W1, b1, W2, b2, out);
}

// Round 6
// 307.169 us; speedup vs baseline: 1.3000x; 1.3000x over previous
//
#include <hip/hip_runtime.h>
#include <stdint.h>

#define NN 100000
#define NE 1600000
#define NG 1000
#define FIN 128
#define DIM 32
#define NC 10

#define NBKT 512          // super-buckets over dst nodes
#define NPB 196           // nodes per bucket (512*196 = 100352 >= NN)
#define BCAP 4608         // edges per bucket (mean 3136 + pad8 ~686 = 3822, ~13 sigma headroom)
#define RND 4096          // edges per binning block (16/thread in regs)
#define CURS 16           // cursor stride in ints (one per 64-B line)
#define NBINB 391         // binning blocks (391*4096 >= NE)
#define MM1P1 781         // mm1 blocks co-dispatched with bin
#define MM1P2 782         // mm1 blocks co-dispatched with csr

typedef unsigned int u32;
typedef __attribute__((ext_vector_type(8))) short short8;
typedef __attribute__((ext_vector_type(4))) float floatx4;
typedef __attribute__((ext_vector_type(4))) unsigned int uint4e;

__device__ __forceinline__ ushort f2bf(float f) {
    u32 b = __float_as_uint(f);
    return (ushort)((b + 0x7FFFu + ((b >> 16) & 1u)) >> 16);   // RNE
}
__device__ __forceinline__ float bf2f(ushort u) {
    return __uint_as_float(((u32)u) << 16);
}

// per-kernel shared unions (keep each as small as possible for occupancy)
struct SBin {                  // 4 KB (no staging: direct global scatter, csr re-sorts anyway)
    int cnt[NBKT]; int gbase[NBKT];
};
struct SCsr {                  // 1.6 KB
    int hist[NPB]; int base[NPB]; int wsum[4];
};
struct SMm {                   // 17.4 KB (x tile only; W frags precomputed)
    ushort xs[64 * 136];
};
union SMem1 { SBin b; SMm m; };   // pre1: 17.4 KB -> 8 blocks/CU
union SMem2 { SCsr c; SMm m; };   // pre2: 17.4 KB -> 8 blocks/CU

// ---------------- init: zero cursor+pool, build bf16 W fragments for all layers ----------------
__global__ __launch_bounds__(256) void k_init(u32* __restrict__ zp, int zn,
        const float* __restrict__ W0r, const float* __restrict__ W0o,
        const float* __restrict__ W1r, const float* __restrict__ W1o,
        const float* __restrict__ W2r, const float* __restrict__ W2o,
        const float* __restrict__ W3r, const float* __restrict__ W3o,
        const float* __restrict__ W4r, const float* __restrict__ W4o,
        ushort* __restrict__ wfrag, ushort* __restrict__ wfrag1) {
    int i = blockIdx.x * 256 + threadIdx.x;
    if (i < zn) zp[i] = 0u;
    int t = threadIdx.x;
    int mat  = t >> 7;          // 0 = rel, 1 = root
    int nh   = (t >> 6) & 1;    // output-col half
    int lane = t & 63;
    int m = lane & 15;          // col within tile
    int g = lane >> 4;          // k-group
    if (blockIdx.x < 4) {       // layers 2..5 (DIM x DIM): one k-chunk each
        const float* Ws[8] = {W1r, W1o, W2r, W2o, W3r, W3o, W4r, W4o};
        const float* W = Ws[blockIdx.x * 2 + mat];
        ushort* dst = wfrag + (((size_t)blockIdx.x * 4 + mat * 2 + nh) * 64 + lane) * 8;
        #pragma unroll
        for (int j = 0; j < 8; ++j)
            dst[j] = f2bf(W[(g * 8 + j) * DIM + nh * 16 + m]);
    } else if (blockIdx.x < 8) { // layer 1 (FIN x DIM): 4 k-chunks
        int kc = blockIdx.x - 4;
        const float* W = mat ? W0o : W0r;
        int nt = mat * 2 + nh;
        ushort* dst = wfrag1 + (((size_t)nt * 4 + kc) * 64 + lane) * 8;
        #pragma unroll
        for (int j = 0; j < 8; ++j)
            dst[j] = f2bf(W[(kc * 32 + g * 8 + j) * DIM + nh * 16 + m]);
    }
}

// ---------------- bodies ----------------
// bin: count-rank via LDS atomics, one cursor atomic per bucket, direct global scatter
// (arrival order within bucket is fine: csr re-sorts by loc)
__device__ void bin_body(SMem1& sm, int blk, const int* __restrict__ ei,
        const float* __restrict__ ew, int* __restrict__ cursor,
        uint2* __restrict__ ebuf) {
    int tid = threadIdx.x;
    int e0 = blk * RND;
    int n  = min(RND, NE - e0);

    for (int i = tid; i < NBKT; i += 256) sm.b.cnt[i] = 0;
    __syncthreads();

    u32 pk[16], wvv[16], bp[16];
    #pragma unroll
    for (int q = 0; q < 16; ++q) {
        int i = tid + q * 256;
        bp[q] = 0xFFFFFFFFu;
        if (i < n) {
            int s = ei[e0 + i];
            int d = ei[NE + e0 + i];
            float w = ew[e0 + i];
            int b = d / NPB;
            int loc = d - b * NPB;
            int p = atomicAdd(&sm.b.cnt[b], 1);
            pk[q]  = (u32)s | ((u32)loc << 17);
            wvv[q] = __float_as_uint(w);
            bp[q]  = (u32)p | ((u32)b << 16);
        }
    }
    __syncthreads();

    for (int i = tid; i < NBKT; i += 256) {
        int c = sm.b.cnt[i];
        sm.b.gbase[i] = (c > 0) ? atomicAdd(&cursor[i * CURS], c) : 0;
    }
    __syncthreads();

    #pragma unroll
    for (int q = 0; q < 16; ++q) {
        if (bp[q] != 0xFFFFFFFFu) {
            int b = (int)(bp[q] >> 16);
            int p = (int)(bp[q] & 0xFFFFu);
            int pos = sm.b.gbase[b] + p;
            if (pos < BCAP) ebuf[(size_t)b * BCAP + pos] = make_uint2(pk[q], wvv[q]);
        }
    }
}

// csr: rank-sort bucket, emit 4-B gather records: src(17b) | wbf16(15b, sign always 0)<<17
__device__ void csr_body(SMem2& sm, int bkt, const uint2* __restrict__ ebuf,
        u32* __restrict__ gbuf, const int* __restrict__ cursor, uint2* __restrict__ od) {
    int tid = threadIdx.x;
    int lane = tid & 63, wvx = tid >> 6;
    int cnt = min(cursor[bkt * CURS], 4096);     // 16 regs/thread capacity
    for (int i = tid; i < NPB; i += 256) sm.c.hist[i] = 0;
    __syncthreads();
    const uint2* gb = ebuf + (size_t)bkt * BCAP;
    u32* gB = gbuf + (size_t)bkt * BCAP;
    uint2 my[16]; int mp[16];
    #pragma unroll
    for (int q = 0; q < 16; ++q) {
        int i = tid + q * 256;
        mp[q] = -1;
        if (i < cnt) {
            my[q] = gb[i];
            int loc = (int)(my[q].x >> 17);
            mp[q] = atomicAdd(&sm.c.hist[loc], 1);
        }
    }
    __syncthreads();
    // padded (x8) exclusive scan over 196 hist entries via wave shuffles
    int h  = (tid < NPB) ? sm.c.hist[tid] : 0;
    int hp = (h + 7) & ~7;
    int inc = hp;
    #pragma unroll
    for (int d = 1; d < 64; d <<= 1) {
        int u = __shfl_up(inc, d);
        if (lane >= d) inc += u;
    }
    if (lane == 63) sm.c.wsum[wvx] = inc;
    __syncthreads();
    int off = 0;
    #pragma unroll
    for (int w2 = 0; w2 < 3; ++w2) off += (w2 < wvx) ? sm.c.wsum[w2] : 0;
    if (tid < NPB) sm.c.base[tid] = off + inc - hp;
    __syncthreads();
    int tot = sm.c.wsum[0] + sm.c.wsum[1] + sm.c.wsum[2] + sm.c.wsum[3];
    tot = min(tot, BCAP);
    // zero-fill padded region (coalesced), then scatter 4-B records (L2-resident bucket)
    for (int i = tid; i < tot; i += 256) gB[i] = 0u;
    __syncthreads();
    #pragma unroll
    for (int q = 0; q < 16; ++q) {
        if (mp[q] >= 0) {
            int loc = (int)(my[q].x >> 17);
            int pos = sm.c.base[loc] + mp[q];
            if (pos < BCAP)
                gB[pos] = (my[q].x & 0x1FFFFu)
                        | ((u32)f2bf(__uint_as_float(my[q].y)) << 17);
        }
    }
    for (int i = tid; i < NPB; i += 256) {
        int node = bkt * NPB + i;
        if (node < NN) {
            int dg = sm.c.hist[i];
            int bs = sm.c.base[i];
            if (bs + ((dg + 7) & ~7) > BCAP) dg = max(0, BCAP - bs) & ~7;   // ~never
            od[node] = make_uint2((u32)(bkt * BCAP + bs), (u32)dg);
        }
    }
}

__device__ void mm1_body(ushort* __restrict__ xs, int blk, const float* __restrict__ x,
        const ushort* __restrict__ wfrag1, const float* __restrict__ brel,
        ushort* __restrict__ ybf, ushort* __restrict__ aggb) {
    int tid = threadIdx.x;
    int base = blk * 64;
    for (int i = tid; i < 64 * 32; i += 256) {
        int r = i >> 5, c = i & 31;
        int node = base + r;
        float4 v = make_float4(0.f, 0.f, 0.f, 0.f);
        if (node < NN) v = ((const float4*)x)[(size_t)node * 32 + c];
        ushort4 u;
        u.x = f2bf(v.x); u.y = f2bf(v.y); u.z = f2bf(v.z); u.w = f2bf(v.w);
        *(ushort4*)&xs[r * 136 + c * 4] = u;
    }
    int lane = tid & 63;
    int w = tid >> 6;
    int m = lane & 15;
    int q = lane >> 4;
    short8 bfr[4][4];
    #pragma unroll
    for (int nt = 0; nt < 4; ++nt)
        #pragma unroll
        for (int kc = 0; kc < 4; ++kc)
            bfr[nt][kc] = *(const short8*)&wfrag1[(((size_t)nt * 4 + kc) * 64 + lane) * 8];
    __syncthreads();
    floatx4 acc[4] = {{0.f,0.f,0.f,0.f},{0.f,0.f,0.f,0.f},{0.f,0.f,0.f,0.f},{0.f,0.f,0.f,0.f}};
    #pragma unroll
    for (int kc = 0; kc < 4; ++kc) {
        short8 af = *(const short8*)&xs[(w * 16 + m) * 136 + kc * 32 + q * 8];
        #pragma unroll
        for (int nt = 0; nt < 4; ++nt)
            acc[nt] = __builtin_amdgcn_mfma_f32_16x16x32_bf16(af, bfr[nt][kc], acc[nt], 0, 0, 0);
    }
    float br0 = brel[m], br1 = brel[16 + m];
    #pragma unroll
    for (int reg = 0; reg < 4; ++reg) {
        int row = q * 4 + reg;
        int node = base + w * 16 + row;
        if (node < NN) {
            ybf[(size_t)node * 32 + m]       = f2bf(acc[0][reg]);
            ybf[(size_t)node * 32 + 16 + m]  = f2bf(acc[1][reg]);
            aggb[(size_t)node * 32 + m]      = f2bf(acc[2][reg] + br0);
            aggb[(size_t)node * 32 + 16 + m] = f2bf(acc[3][reg] + br1);
        }
    }
}

// ---------------- combined dispatches: bin || mm1-half1, csr || mm1-half2 ----------------
__global__ __launch_bounds__(256, 8) void k_pre1(const int* __restrict__ ei,
        const float* __restrict__ ew, int* __restrict__ cursor, uint2* __restrict__ ebuf,
        const float* __restrict__ x, const ushort* __restrict__ wfrag1,
        const float* __restrict__ brel,
        ushort* __restrict__ ybf, ushort* __restrict__ aggb) {
    __shared__ SMem1 sm;
    if (blockIdx.x < NBINB) bin_body(sm, blockIdx.x, ei, ew, cursor, ebuf);
    else                    mm1_body(sm.m.xs, blockIdx.x - NBINB, x, wfrag1, brel, ybf, aggb);
}

__global__ __launch_bounds__(256, 8) void k_pre2(const uint2* __restrict__ ebuf,
        u32* __restrict__ gbuf, const int* __restrict__ cursor, uint2* __restrict__ od,
        const float* __restrict__ x, const ushort* __restrict__ wfrag1,
        const float* __restrict__ brel,
        ushort* __restrict__ ybf, ushort* __restrict__ aggb) {
    __shared__ SMem2 sm;
    if (blockIdx.x < NBKT) csr_body(sm, blockIdx.x, ebuf, gbuf, cursor, od);
    else                   mm1_body(sm.m.xs, blockIdx.x - NBKT + MM1P1, x, wfrag1, brel, ybf, aggb);
}

// ---------------- packed 2-feature gather: 16 lanes/node, 4-B records, 16-edge strips ----
// record: src(17b) | wbf16-sans-sign(15b)<<17; w = bits ((e & 0xFFFE0000) >> 1)
// pad-to-8 invariant: a 16-strip at b is entered only when deg >= b+9, so padded len >= b+16
__device__ __forceinline__ float2 gather_accum(const u32* __restrict__ eb, int deg,
        const uint* __restrict__ ybp) {
    float acc0 = 0.f, acc1 = 0.f;
    int b = 0;
    for (; b + 8 < deg; b += 16) {
        const uint4e* p = (const uint4e*)(eb + b);
        uint4e a0 = __builtin_nontemporal_load(p + 0);
        uint4e a1 = __builtin_nontemporal_load(p + 1);
        uint4e a2 = __builtin_nontemporal_load(p + 2);
        uint4e a3 = __builtin_nontemporal_load(p + 3);
        uint u0  = ybp[(a0.x & 0x1FFFFu) << 4];
        uint u1  = ybp[(a0.y & 0x1FFFFu) << 4];
        uint u2  = ybp[(a0.z & 0x1FFFFu) << 4];
        uint u3  = ybp[(a0.w & 0x1FFFFu) << 4];
        uint u4  = ybp[(a1.x & 0x1FFFFu) << 4];
        uint u5  = ybp[(a1.y & 0x1FFFFu) << 4];
        uint u6  = ybp[(a1.z & 0x1FFFFu) << 4];
        uint u7  = ybp[(a1.w & 0x1FFFFu) << 4];
        uint u8  = ybp[(a2.x & 0x1FFFFu) << 4];
        uint u9  = ybp[(a2.y & 0x1FFFFu) << 4];
        uint u10 = ybp[(a2.z & 0x1FFFFu) << 4];
        uint u11 = ybp[(a2.w & 0x1FFFFu) << 4];
        uint u12 = ybp[(a3.x & 0x1FFFFu) << 4];
        uint u13 = ybp[(a3.y & 0x1FFFFu) << 4];
        uint u14 = ybp[(a3.z & 0x1FFFFu) << 4];
        uint u15 = ybp[(a3.w & 0x1FFFFu) << 4];
        float w;
        w = __uint_as_float((a0.x & 0xFFFE0000u) >> 1);
        acc0 += w * __uint_as_float(u0 << 16);  acc1 += w * __uint_as_float(u0 & 0xFFFF0000u);
        w = __uint_as_float((a0.y & 0xFFFE0000u) >> 1);
        acc0 += w * __uint_as_float(u1 << 16);  acc1 += w * __uint_as_float(u1 & 0xFFFF0000u);
        w = __uint_as_float((a0.z & 0xFFFE0000u) >> 1);
        acc0 += w * __uint_as_float(u2 << 16);  acc1 += w * __uint_as_float(u2 & 0xFFFF0000u);
        w = __uint_as_float((a0.w & 0xFFFE0000u) >> 1);
        acc0 += w * __uint_as_float(u3 << 16);  acc1 += w * __uint_as_float(u3 & 0xFFFF0000u);
        w = __uint_as_float((a1.x & 0xFFFE0000u) >> 1);
        acc0 += w * __uint_as_float(u4 << 16);  acc1 += w * __uint_as_float(u4 & 0xFFFF0000u);
        w = __uint_as_float((a1.y & 0xFFFE0000u) >> 1);
        acc0 += w * __uint_as_float(u5 << 16);  acc1 += w * __uint_as_float(u5 & 0xFFFF0000u);
        w = __uint_as_float((a1.z & 0xFFFE0000u) >> 1);
        acc0 += w * __uint_as_float(u6 << 16);  acc1 += w * __uint_as_float(u6 & 0xFFFF0000u);
        w = __uint_as_float((a1.w & 0xFFFE0000u) >> 1);
        acc0 += w * __uint_as_float(u7 << 16);  acc1 += w * __uint_as_float(u7 & 0xFFFF0000u);
        w = __uint_as_float((a2.x & 0xFFFE0000u) >> 1);
        acc0 += w * __uint_as_float(u8 << 16);  acc1 += w * __uint_as_float(u8 & 0xFFFF0000u);
        w = __uint_as_float((a2.y & 0xFFFE0000u) >> 1);
        acc0 += w * __uint_as_float(u9 << 16);  acc1 += w * __uint_as_float(u9 & 0xFFFF0000u);
        w = __uint_as_float((a2.z & 0xFFFE0000u) >> 1);
        acc0 += w * __uint_as_float(u10 << 16); acc1 += w * __uint_as_float(u10 & 0xFFFF0000u);
        w = __uint_as_float((a2.w & 0xFFFE0000u) >> 1);
        acc0 += w * __uint_as_float(u11 << 16); acc1 += w * __uint_as_float(u11 & 0xFFFF0000u);
        w = __uint_as_float((a3.x & 0xFFFE0000u) >> 1);
        acc0 += w * __uint_as_float(u12 << 16); acc1 += w * __uint_as_float(u12 & 0xFFFF0000u);
        w = __uint_as_float((a3.y & 0xFFFE0000u) >> 1);
        acc0 += w * __uint_as_float(u13 << 16); acc1 += w * __uint_as_float(u13 & 0xFFFF0000u);
        w = __uint_as_float((a3.z & 0xFFFE0000u) >> 1);
        acc0 += w * __uint_as_float(u14 << 16); acc1 += w * __uint_as_float(u14 & 0xFFFF0000u);
        w = __uint_as_float((a3.w & 0xFFFE0000u) >> 1);
        acc0 += w * __uint_as_float(u15 << 16); acc1 += w * __uint_as_float(u15 & 0xFFFF0000u);
    }
    if (b < deg) {                                  // 8-edge tail (deg%16 in 1..8)
        const uint4e* p = (const uint4e*)(eb + b);
        uint4e a0 = __builtin_nontemporal_load(p + 0);
        uint4e a1 = __builtin_nontemporal_load(p + 1);
        uint u0 = ybp[(a0.x & 0x1FFFFu) << 4];
        uint u1 = ybp[(a0.y & 0x1FFFFu) << 4];
        uint u2 = ybp[(a0.z & 0x1FFFFu) << 4];
        uint u3 = ybp[(a0.w & 0x1FFFFu) << 4];
        uint u4 = ybp[(a1.x & 0x1FFFFu) << 4];
        uint u5 = ybp[(a1.y & 0x1FFFFu) << 4];
        uint u6 = ybp[(a1.z & 0x1FFFFu) << 4];
        uint u7 = ybp[(a1.w & 0x1FFFFu) << 4];
        float w;
        w = __uint_as_float((a0.x & 0xFFFE0000u) >> 1);
        acc0 += w * __uint_as_float(u0 << 16);  acc1 += w * __uint_as_float(u0 & 0xFFFF0000u);
        w = __uint_as_float((a0.y & 0xFFFE0000u) >> 1);
        acc0 += w * __uint_as_float(u1 << 16);  acc1 += w * __uint_as_float(u1 & 0xFFFF0000u);
        w = __uint_as_float((a0.z & 0xFFFE0000u) >> 1);
        acc0 += w * __uint_as_float(u2 << 16);  acc1 += w * __uint_as_float(u2 & 0xFFFF0000u);
        w = __uint_as_float((a0.w & 0xFFFE0000u) >> 1);
        acc0 += w * __uint_as_float(u3 << 16);  acc1 += w * __uint_as_float(u3 & 0xFFFF0000u);
        w = __uint_as_float((a1.x & 0xFFFE0000u) >> 1);
        acc0 += w * __uint_as_float(u4 << 16);  acc1 += w * __uint_as_float(u4 & 0xFFFF0000u);
        w = __uint_as_float((a1.y & 0xFFFE0000u) >> 1);
        acc0 += w * __uint_as_float(u5 << 16);  acc1 += w * __uint_as_float(u5 & 0xFFFF0000u);
        w = __uint_as_float((a1.z & 0xFFFE0000u) >> 1);
        acc0 += w * __uint_as_float(u6 << 16);  acc1 += w * __uint_as_float(u6 & 0xFFFF0000u);
        w = __uint_as_float((a1.w & 0xFFFE0000u) >> 1);
        acc0 += w * __uint_as_float(u7 << 16);  acc1 += w * __uint_as_float(u7 & 0xFFFF0000u);
    }
    return make_float2(acc0, acc1);
}

// ---------------- fused gather + relu + next-layer dual matmul (MFMA) ----------------
// 16 nodes/block, 4 waves: wave w computes one 16x16 output tile (mat = w>>1, colhalf = w&1)
__global__ __launch_bounds__(256, 6) void k_gfused(const ushort* __restrict__ ybf,
        const u32* __restrict__ gbuf, const uint2* __restrict__ od,
        const ushort* __restrict__ aggb, const ushort* __restrict__ wfragL,
        const float* __restrict__ brel,
        ushort* __restrict__ ybf_n, ushort* __restrict__ aggb_n) {
    __shared__ __align__(16) ushort hsm[16 * 40];   // h tile, bf16, pitch 40 shorts
    int tid  = threadIdx.x;
    int w    = tid >> 6;
    int lane = tid & 63;
    int nl   = lane >> 4;        // node within wave
    int fp   = lane & 15;        // feature pair index
    int node = blockIdx.x * 16 + w * 4 + nl;
    // wave-specific W fragment (precomputed bf16, fragment-major): one 16-B load
    short8 bfr = *(const short8*)&wfragL[((size_t)w * 64 + lane) * 8];
    uint2 o = od[node];
    const u32* eb = gbuf + o.x;
    const uint* ybp = (const uint*)ybf + fp;
    uint pa = ((const uint*)aggb)[node * 16 + fp];     // packed bf16 pair (2fp, 2fp+1)
    float2 ac = gather_accum(eb, (int)o.y, ybp);
    float h0 = fmaxf(__uint_as_float(pa << 16) + ac.x, 0.f);
    float h1 = fmaxf(__uint_as_float(pa & 0xFFFF0000u) + ac.y, 0.f);
    u32 hp = (u32)f2bf(h0) | ((u32)f2bf(h1) << 16);
    *(u32*)&hsm[(w * 4 + nl) * 40 + fp * 2] = hp;
    __syncthreads();
    // A fragment: lane reads h[row = lane&15][k = (lane>>4)*8 .. +7]
    short8 af = *(const short8*)&hsm[(lane & 15) * 40 + (lane >> 4) * 8];
    floatx4 acc = {0.f, 0.f, 0.f, 0.f};
    acc = __builtin_amdgcn_mfma_f32_16x16x32_bf16(af, bfr, acc, 0, 0, 0);
    int ncol  = (w & 1) * 16 + (lane & 15);
    int drow0 = (lane >> 4) * 4;
    size_t obase = ((size_t)blockIdx.x * 16 + drow0) * DIM + ncol;
    if (w < 2) {                                   // rel path -> y (bf16)
        #pragma unroll
        for (int r = 0; r < 4; ++r)
            ybf_n[obase + (size_t)r * DIM] = f2bf(acc[r]);
    } else {                                       // root path + bias -> agg init (bf16)
        float bb = brel[ncol];
        #pragma unroll
        for (int r = 0; r < 4; ++r)
            aggb_n[obase + (size_t)r * DIM] = f2bf(acc[r] + bb);
    }
}

// ---------------- fused last gather + relu + pool ----------------
__global__ __launch_bounds__(256, 6) void k_glast_pool(const ushort* __restrict__ ybf,
        const u32* __restrict__ gbuf, const uint2* __restrict__ od,
        const ushort* __restrict__ aggb, const int* __restrict__ batch,
        float* __restrict__ g) {
    __shared__ __align__(16) float hsm[16][34];
    int tid  = threadIdx.x;
    int w    = tid >> 6;
    int lane = tid & 63;
    int nl   = lane >> 4;
    int fp   = lane & 15;
    int node = blockIdx.x * 16 + w * 4 + nl;
    uint2 o = od[node];
    const u32* eb = gbuf + o.x;
    const uint* ybp = (const uint*)ybf + fp;
    uint pa = ((const uint*)aggb)[node * 16 + fp];
    float2 ac = gather_accum(eb, (int)o.y, ybp);
    float2 hv;
    hv.x = fmaxf(__uint_as_float(pa << 16) + ac.x, 0.f);
    hv.y = fmaxf(__uint_as_float(pa & 0xFFFF0000u) + ac.y, 0.f);
    *(float2*)&hsm[w * 4 + nl][fp * 2] = hv;
    __syncthreads();
    if (tid < 32) {                            // segmented sum over 16 sorted nodes
        int nb = blockIdx.x * 16;
        int curb = batch[nb];
        float run = 0.f;
        #pragma unroll
        for (int n = 0; n < 16; ++n) {
            int b = batch[nb + n];
            if (b != curb) {
                atomicAdd(&g[(size_t)curb * DIM + tid], run);
                run = 0.f; curb = b;
            }
            run += hsm[n][tid];
        }
        atomicAdd(&g[(size_t)curb * DIM + tid], run);
    }
}

// ---------------- head ----------------
__global__ __launch_bounds__(64) void k_head(const float* __restrict__ g,
        const float* __restrict__ W1, const float* __restrict__ b1,
        const float* __restrict__ W2, const float* __restrict__ b2,
        float* __restrict__ out) {
    __shared__ float gs[DIM];
    __shared__ float a1[DIM];
    __shared__ float lg[NC];
    int t = threadIdx.x;
    int gr = blockIdx.x;
    if (t < DIM) gs[t] = g[(size_t)gr * DIM + t];
    __syncthreads();
    if (t < DIM) {
        float a = b1[t];
        #pragma unroll
        for (int k = 0; k < DIM; ++k) a += gs[k] * W1[k * DIM + t];
        a1[t] = fmaxf(a, 0.f);
    }
    __syncthreads();
    if (t < NC) {
        float a = b2[t];
        #pragma unroll
        for (int k = 0; k < DIM; ++k) a += a1[k] * W2[k * NC + t];
        lg[t] = a;
    }
    __syncthreads();
    if (t == 0) {
        float m = lg[0];
        for (int c = 1; c < NC; ++c) m = fmaxf(m, lg[c]);
        float s = 0.f;
        for (int c = 0; c < NC; ++c) s += expf(lg[c] - m);
        float ls = m + logf(s);
        for (int c = 0; c < NC; ++c) out[(size_t)gr * NC + c] = lg[c] - ls;
    }
}

extern "C" void kernel_launch(void* const* d_in, const int* in_sizes, int n_in,
                              void* d_out, int out_size, void* d_ws, size_t ws_size,
                              hipStream_t stream) {
    const float* x     = (const float*)d_in[0];
    const int*   ei    = (const int*)d_in[1];
    const int*   batch = (const int*)d_in[2];
    const float* ew    = (const float*)d_in[3];
    const float* Wrel[5]  = {(const float*)d_in[4],  (const float*)d_in[7],  (const float*)d_in[10], (const float*)d_in[13], (const float*)d_in[16]};
    const float* brel[5]  = {(const float*)d_in[5],  (const float*)d_in[8],  (const float*)d_in[11], (const float*)d_in[14], (const float*)d_in[17]};
    const float* Wroot[5] = {(const float*)d_in[6],  (const float*)d_in[9],  (const float*)d_in[12], (const float*)d_in[15], (const float*)d_in[18]};
    const float* W1 = (const float*)d_in[19];
    const float* b1 = (const float*)d_in[20];
    const float* W2 = (const float*)d_in[21];
    const float* b2 = (const float*)d_in[22];
    float* out = (float*)d_out;

    char* ws = (char*)d_ws;
    const size_t off_cursor = 0;                                   // 32768
    const size_t off_g      = 32768;                               // 128000
    const size_t zero_end   = 160768;
    const size_t off_wfrag  = 160768;                              // layers 2-5: 16384 B
    const size_t off_wfrag1 = 177152;                              // layer 1: 16384 B
    const size_t off_ebuf   = 193536;                              // 16-B aligned
    const size_t ebuf_bytes = ((size_t)NBKT * BCAP + 64) * 8;      // staging (uint2)
    const size_t off_gbuf   = off_ebuf + ebuf_bytes;               // gather records (u32)
    const size_t gbuf_bytes = ((size_t)NBKT * BCAP + 64) * 4;
    const size_t off_od     = off_gbuf + gbuf_bytes;
    const size_t off_A      = off_od + (size_t)NN * 8;             // aggb ping (bf16)
    const size_t off_C      = off_A + (size_t)NN * DIM * 2;        // aggb pong (bf16)
    const size_t off_B1     = off_C + (size_t)NN * DIM * 2;        // y ping (bf16)
    const size_t off_B2     = off_B1 + (size_t)NN * DIM * 2;       // y pong (bf16)
    const size_t need       = off_B2 + (size_t)NN * DIM * 2;       // ~54.9 MB
    if (ws_size < need) return;

    int*    cursor = (int*)(ws + off_cursor);
    float*  g      = (float*)(ws + off_g);
    ushort* wfrag  = (ushort*)(ws + off_wfrag);
    ushort* wfrag1 = (ushort*)(ws + off_wfrag1);
    uint2*  ebuf   = (uint2*)(ws + off_ebuf);
    u32*    gbuf   = (u32*)(ws + off_gbuf);
    uint2*  od     = (uint2*)(ws + off_od);
    ushort* A      = (ushort*)(ws + off_A);
    ushort* C      = (ushort*)(ws + off_C);
    ushort* B1     = (ushort*)(ws + off_B1);
    ushort* B2     = (ushort*)(ws + off_B2);

    int zcount = (int)(zero_end / 4);
    k_init<<<(zcount + 255) / 256, 256, 0, stream>>>((u32*)ws, zcount,
        Wrel[0], Wroot[0], Wrel[1], Wroot[1], Wrel[2], Wroot[2],
        Wrel[3], Wroot[3], Wrel[4], Wroot[4], wfrag, wfrag1);

    // combined: binning || mm1 first half, then csr || mm1 second half
    k_pre1<<<NBINB + MM1P1, 256, 0, stream>>>(ei, ew, cursor, ebuf,
                                              x, wfrag1, brel[0], B1, A);
    k_pre2<<<NBKT + MM1P2, 256, 0, stream>>>(ebuf, gbuf, cursor, od,
                                             x, wfrag1, brel[0], B1, A);

    const int ngt = NN / 16;                   // 6250 (exact)
    ushort* aggc = A;  ushort* aggn = C;
    ushort* yc   = B1; ushort* yn   = B2;
    for (int L = 1; L < 5; ++L) {
        k_gfused<<<ngt, 256, 0, stream>>>(yc, gbuf, od, aggc,
                                          wfrag + (size_t)(L - 1) * 2048, brel[L], yn, aggn);
        ushort* tf = aggc; aggc = aggn; aggn = tf;
        ushort* tu = yc; yc = yn; yn = tu;
    }
    k_glast_pool<<<ngt, 256, 0, stream>>>(yc, gbuf, od, aggc, batch, g);
    k_head<<<NG, 64, 0, stream>>>(g, W1, b1, W2, b2, out);
}